// Round 5
// baseline (1464.888 us; speedup 1.0000x reference)
//
#include <hip/hip_runtime.h>
#include <float.h>

// Problem constants (match reference): B=32, N=M=128, D=256, WEIGHT=1.0
#define Bc 32
#define Nn 128
#define Dd 256

// ---------------------------------------------------------------------------
// DPP helpers. dpp_ctrl must be a compile-time constant.
// ---------------------------------------------------------------------------
template <int CTRL>
__device__ __forceinline__ float dpp_addsrc(float x) {  // old = 0 for untouched lanes
    return __int_as_float(__builtin_amdgcn_update_dpp(0, __float_as_int(x), CTRL,
                                                      0xf, 0xf, false));
}
__device__ __forceinline__ float wave_sum_lane63(float x) {
    x += dpp_addsrc<0x121>(x);  // row_ror:1
    x += dpp_addsrc<0x122>(x);  // row_ror:2
    x += dpp_addsrc<0x124>(x);  // row_ror:4
    x += dpp_addsrc<0x128>(x);  // row_ror:8
    x += dpp_addsrc<0x142>(x);  // row_bcast:15
    x += dpp_addsrc<0x143>(x);  // row_bcast:31
    return x;                   // lane 63 = total
}

template <int CTRL>
__device__ __forceinline__ unsigned dpp_movu(unsigned x) {  // old = UINT_MAX
    return (unsigned)__builtin_amdgcn_update_dpp((int)0xFFFFFFFFu, (int)x, CTRL,
                                                 0xf, 0xf, false);
}
__device__ __forceinline__ unsigned wave_umin_lane63(unsigned x) {
    x = min(x, dpp_movu<0x121>(x));
    x = min(x, dpp_movu<0x122>(x));
    x = min(x, dpp_movu<0x124>(x));
    x = min(x, dpp_movu<0x128>(x));
    x = min(x, dpp_movu<0x142>(x));
    x = min(x, dpp_movu<0x143>(x));
    return x;                   // lane 63 = min of all 64 lanes
}

template <int CTRL>
__device__ __forceinline__ float dpp_movf(float x) {  // old = FLT_MAX
    return __int_as_float(__builtin_amdgcn_update_dpp(0x7f7fffff, __float_as_int(x),
                                                      CTRL, 0xf, 0xf, false));
}
// two-min (min, second-min counting multiplicity) combine step
template <int CTRL>
__device__ __forceinline__ void dpp2min_step(float& m1, float& m2) {
    float o1 = dpp_movf<CTRL>(m1);
    float o2 = dpp_movf<CTRL>(m2);
    float n1 = fminf(m1, o1);
    m2 = fminf(fmaxf(m1, o1), fminf(m2, o2));
    m1 = n1;
}

__device__ __forceinline__ float readlane_f(float v, int lane) {
    return __int_as_float(__builtin_amdgcn_readlane(__float_as_int(v), lane));
}

// ---------------------------------------------------------------------------
// Kernel 1: pairwise MSE cost.  cost[b,i,j] = sum_d (p[b,i,d]-g[b,j,d])^2 / D
// ---------------------------------------------------------------------------
__global__ __launch_bounds__(64) void cost_kernel(const float* __restrict__ P,
                                                  const float* __restrict__ G,
                                                  float* __restrict__ C,
                                                  float* __restrict__ out) {
    const int b = blockIdx.y;
    const int i = blockIdx.x;
    const int t = threadIdx.x;

    if (b == 0 && i == 0 && t == 0) *out = 0.0f;

    const float4 pv = ((const float4*)(P + ((size_t)b * Nn + i) * Dd))[t];
    const float4* g4 = (const float4*)(G + (size_t)b * Nn * Dd);
    float* crow = C + ((size_t)b * Nn + i) * Nn;

    for (int j = 0; j < Nn; j += 2) {
        float4 gv0 = g4[(size_t)j * 64 + t];
        float4 gv1 = g4[(size_t)(j + 1) * 64 + t];
        float dx0 = pv.x - gv0.x, dy0 = pv.y - gv0.y, dz0 = pv.z - gv0.z, dw0 = pv.w - gv0.w;
        float dx1 = pv.x - gv1.x, dy1 = pv.y - gv1.y, dz1 = pv.z - gv1.z, dw1 = pv.w - gv1.w;
        float s0 = dx0 * dx0 + dy0 * dy0 + dz0 * dz0 + dw0 * dw0;
        float s1 = dx1 * dx1 + dy1 * dy1 + dz1 * dz1 + dw1 * dw1;
        s0 = wave_sum_lane63(s0);
        s1 = wave_sum_lane63(s1);
        if (t == 63) {
            crow[j]     = s0 * (1.0f / (float)Dd);
            crow[j + 1] = s1 * (1.0f / (float)Dd);
        }
    }
}

// ---------------------------------------------------------------------------
// Phases 1 + 1.5 + 2 for one batch (verbatim R2 bodies, parameterized).
// References resolve to caller registers (forceinline).
// ---------------------------------------------------------------------------
__device__ __forceinline__ void phases12(const float* __restrict__ CS, int* clm, int t,
        float& vA, float& vB, float& uA, float& uB, float& wA, float& wB,
        int& pA, int& pB, unsigned long long& fmA, unsigned long long& fmB) {
    // ---- Phase 1: column reduction ----
    float bestA = FLT_MAX, bestB = FLT_MAX;
    int argA = 0, argB = 0;
    for (int i = 0; i < Nn; ++i) {
        float c0 = CS[i * Nn + t];
        float c1 = CS[i * Nn + t + 64];
        if (c0 < bestA) { bestA = c0; argA = i; }
        if (c1 < bestB) { bestB = c1; argB = i; }
    }
    vA = bestA; vB = bestB;
    atomicMin(&clm[argA], t);
    atomicMin(&clm[argB], t + 64);
    __syncthreads();

    uA = 0.0f; uB = 0.0f; wA = 0.0f; wB = 0.0f;
    pA = 0; pB = 0;
    if (clm[argA] == t)      pA = argA + 1;
    if (clm[argB] == t + 64) pB = argB + 1;
    fmA = __ballot(clm[t] == 0x7fffffff);
    fmB = __ballot(clm[t + 64] == 0x7fffffff);

    // ---- Phase 1.5: reduction transfer ----
    {
        int rcA = clm[t];
        int rcB = clm[t + 64];
        float c0 = CS[t];
        float c1 = CS[t + 64];
        for (int r = 0; r < Nn; ++r) {
            int s_c = __builtin_amdgcn_readlane((r & 64) ? rcB : rcA, r & 63);
            int pr = (r + 1) & (Nn - 1);
            float n0 = CS[pr * Nn + t];
            float n1 = CS[pr * Nn + t + 64];
            if (s_c != 0x7fffffff) {
                bool ex0 = (t == s_c);
                bool ex1 = (t + 64 == s_c);
                float cur0 = ex0 ? FLT_MAX : (c0 - vA);
                float cur1 = ex1 ? FLT_MAX : (c1 - vB);
                float m = fminf(cur0, cur1);
                m = fminf(m, dpp_movf<0x121>(m));
                m = fminf(m, dpp_movf<0x122>(m));
                m = fminf(m, dpp_movf<0x124>(m));
                m = fminf(m, dpp_movf<0x128>(m));
                m = fminf(m, dpp_movf<0x142>(m));
                m = fminf(m, dpp_movf<0x143>(m));
                float mu = readlane_f(m, 63);
                if (ex0) { vA -= mu; wA = mu; }
                if (ex1) { vB -= mu; wB = mu; }
                if (t == (r & 63)) {
                    if (r < 64) uA = mu; else uB = mu;
                }
            }
            c0 = n0; c1 = n1;
        }
    }

    // ---- Phase 2: augmenting row reduction (2 passes, bounded, with steal) ----
    for (int pass = 0; pass < 2; ++pass) {
        if (!(fmA | fmB)) break;
        unsigned long long remA = fmA, remB = fmB;
        int guard = 0;
        while ((remA | remB) != 0ull && guard++ < 256) {
            int l, i, slotR;
            if (remA) { l = __ffsll(remA) - 1; remA &= remA - 1; i = l + 1;  slotR = 0;
                        if (!((fmA >> l) & 1)) continue; }
            else      { l = __ffsll(remB) - 1; remB &= remB - 1; i = l + 65; slotR = 1;
                        if (!((fmB >> l) & 1)) continue; }

            const float* crow = &CS[(i - 1) * Nn];
            float cur0 = crow[t] - vA;
            float cur1 = crow[t + 64] - vB;
            float m1 = fminf(cur0, cur1);
            float m2 = fmaxf(cur0, cur1);
            dpp2min_step<0x121>(m1, m2);
            dpp2min_step<0x122>(m1, m2);
            dpp2min_step<0x124>(m1, m2);
            dpp2min_step<0x128>(m1, m2);
            dpp2min_step<0x142>(m1, m2);
            dpp2min_step<0x143>(m1, m2);
            float s_m1 = readlane_f(m1, 63);
            float s_m2 = readlane_f(m2, 63);

            unsigned long long b0 = __ballot(cur0 == s_m1);
            unsigned long long b1 = __ballot(cur1 == s_m1);
            int j1 = b0 ? __ffsll(b0) : (__ffsll(b1) + 64);
            int lane1 = (j1 - 1) & 63, slot1 = (j1 - 1) >> 6;

            if (t == l) { if (slotR == 0) uA = s_m2; else uB = s_m2; }

            int k0 = __builtin_amdgcn_readlane(slot1 ? pB : pA, lane1);
            bool strict = (s_m1 < s_m2);
            if (!strict && k0 != 0) continue;

            if (t == lane1) {
                if (slot1 == 0) { vA += s_m1 - s_m2; pA = i; wA = s_m2; }
                else            { vB += s_m1 - s_m2; pB = i; wB = s_m2; }
            }
            if (slotR == 0) fmA &= ~(1ull << l); else fmB &= ~(1ull << l);
            if (k0 != 0) {
                int kl = (k0 - 1) & 63;
                if (k0 <= 64) { fmA |= 1ull << kl; remA |= 1ull << kl; }
                else          { fmB |= 1ull << kl; remB |= 1ull << kl; }
            }
        }
    }
}

// ---------------------------------------------------------------------------
// One Phase-3 tick for one batch. st: 0 = pop next free row, 1 = running,
// 2 = done. One tick = one Dijkstra iteration (verbatim R2 body); on path
// completion the augment walk + next-row init run inline (rare). The row
// prefetch issued at the end of a tick is consumed one full tick later, so
// the OTHER batch's tick body (~130+ cyc) hides the ~120-cyc LDS latency.
// ---------------------------------------------------------------------------
__device__ __forceinline__ void dijk_tick(const float* __restrict__ CS, int t,
        int& st, unsigned long long& mA, unsigned long long& mB,
        int& i_cur, float& s_u, int& s_j0,
        float& vA, float& vB, float& uA, float& uB, float& wA, float& wB,
        int& pA, int& pB,
        float& minvA, float& minvB, int& wayA, int& wayB,
        float& c0, float& c1,
        bool& usedA, bool& usedB, bool& rUA, bool& rUB) {
    if (st == 1) {
        // ---- one Dijkstra iteration ----
        if (!usedA) {
            float cur = fmaxf(c0 - s_u - vA, 0.0f);
            if (cur < minvA) { minvA = cur; wayA = s_j0; }
        }
        if (!usedB) {
            float cur = fmaxf(c1 - s_u - vB, 0.0f);
            if (cur < minvB) { minvB = cur; wayB = s_j0; }
        }

        unsigned kA = (__float_as_uint(usedA ? FLT_MAX : minvA) & 0xFFFFFF00u)
                      | (unsigned)t;
        unsigned kB = (__float_as_uint(usedB ? FLT_MAX : minvB) & 0xFFFFFF00u)
                      | (unsigned)(t + 64);
        unsigned k = wave_umin_lane63(min(kA, kB));
        unsigned s_key = (unsigned)__builtin_amdgcn_readlane((int)k, 63);
        float s_delta = __uint_as_float(s_key & 0xFFFFFF00u);
        int s_j1 = (int)(s_key & 0xFFu) + 1;

        int lane1 = (s_j1 - 1) & 63;
        int slot1 = (s_j1 - 1) >> 6;
        int s_p = __builtin_amdgcn_readlane(slot1 ? pB : pA, lane1);
        float s_w = readlane_f(slot1 ? wB : wA, lane1);

        // prefetch next cost row (consumed NEXT tick; other batch hides it)
        int nrow = (s_p > 0 ? s_p : 1) - 1;
        float nc0 = CS[nrow * Nn + t];
        float nc1 = CS[nrow * Nn + t + 64];

        if (usedA) { vA -= s_delta; wA += s_delta; }
        else       { minvA = fmaxf(minvA - s_delta, 0.0f); }
        if (usedB) { vB -= s_delta; wB += s_delta; }
        else       { minvB = fmaxf(minvB - s_delta, 0.0f); }
        if (rUA) uA += s_delta;
        if (rUB) uB += s_delta;

        if (s_p == 0) {
            // ---- augment along way[] chain (rare; inline) ----
            int s_j = s_j1;
            while (s_j) {
                int lane = (s_j - 1) & 63;
                int slot = (s_j - 1) >> 6;
                int s_jprev = __builtin_amdgcn_readlane(slot ? wayB : wayA, lane);
                int s_pnew;
                if (s_jprev == 0) {
                    s_pnew = i_cur;
                } else {
                    int lp = (s_jprev - 1) & 63;
                    int sp = (s_jprev - 1) >> 6;
                    s_pnew = __builtin_amdgcn_readlane(sp ? pB : pA, lp);
                }
                int rl = (s_pnew - 1) & 63;
                int rs = (s_pnew - 1) >> 6;
                float s_unew = readlane_f(rs ? uB : uA, rl);  // w[j] = u[p[j]]
                if (t == lane) {
                    if (slot == 0) { pA = s_pnew; wA = s_unew; }
                    else           { pB = s_pnew; wB = s_unew; }
                }
                s_j = s_jprev;
            }
            st = 0;  // pop next free row below (same tick)
        } else {
            if (t == lane1) { if (slot1 == 0) usedA = true; else usedB = true; }
            {
                int r = s_p - 1;
                if (t == (r & 63)) { if ((r >> 6) == 0) rUA = true; else rUB = true; }
            }
            s_j0 = s_j1;
            s_u = s_w;
            c0 = nc0;
            c1 = nc1;
        }
    }
    if (st == 0) {
        if ((mA | mB) == 0ull) { st = 2; return; }
        int l, slotR;
        if (mA) { l = __ffsll(mA) - 1; mA &= mA - 1; slotR = 0; }
        else    { l = __ffsll(mB) - 1; mB &= mB - 1; slotR = 1; }
        i_cur = l + 1 + slotR * 64;
        minvA = FLT_MAX; minvB = FLT_MAX;
        wayA = 0; wayB = 0;
        usedA = false; usedB = false;
        rUA = (slotR == 0) && (t == l);
        rUB = (slotR == 1) && (t == l);
        s_j0 = 0;
        s_u = readlane_f(slotR ? uB : uA, l);
        // init row load (consumed next tick; hidden by other batch's tick)
        c0 = CS[(i_cur - 1) * Nn + t];
        c1 = CS[(i_cur - 1) * Nn + t + 64];
        st = 1;
    }
}

// ---------------------------------------------------------------------------
// Kernel 2: LAPJV Hungarian, ONE WAVE PER TWO BATCHES (grid = 16).
// Phases 1/1.5/2 run per batch sequentially; Phase 3 interleaves the two
// independent Dijkstra state machines tick-by-tick so each batch's LDS row
// load hides under the other batch's relax/DPP/readlane work (~95 cyc of
// previously-exposed LDS latency per iteration goes to ~0).
// Dynamic LDS: 2 x 64 KB cost matrices + 2 x 128 claim ints = 129 KiB.
// ---------------------------------------------------------------------------
__global__ __launch_bounds__(64) void hungarian_kernel(const float* __restrict__ Call,
                                                       float* __restrict__ out) {
    const int bid = blockIdx.x;      // 0..15, handles batches 2*bid, 2*bid+1
    const int t = threadIdx.x;

    extern __shared__ __align__(16) float smem[];
    float* Csh0 = smem;                       // 16384 floats
    float* Csh1 = smem + Nn * Nn;             // 16384 floats
    int* claim = (int*)(smem + 2 * Nn * Nn);  // 256 ints

    // stage both batches' cost matrices (coalesced float4)
    {
        const float4* src0 = (const float4*)(Call + (size_t)(2 * bid) * Nn * Nn);
        const float4* src1 = (const float4*)(Call + (size_t)(2 * bid + 1) * Nn * Nn);
        float4* dst0 = (float4*)Csh0;
        float4* dst1 = (float4*)Csh1;
#pragma unroll
        for (int k = 0; k < (Nn * Nn / 4) / 64; ++k) dst0[k * 64 + t] = src0[k * 64 + t];
#pragma unroll
        for (int k = 0; k < (Nn * Nn / 4) / 64; ++k) dst1[k * 64 + t] = src1[k * 64 + t];
    }
    claim[t] = 0x7fffffff;       claim[t + 64] = 0x7fffffff;
    claim[t + 128] = 0x7fffffff; claim[t + 192] = 0x7fffffff;
    __syncthreads();

    // per-batch persistent state
    float vA0, vB0, uA0, uB0, wA0, wB0;
    float vA1, vB1, uA1, uB1, wA1, wB1;
    int pA0, pB0, pA1, pB1;
    unsigned long long fmA0, fmB0, fmA1, fmB1;

    phases12(Csh0, claim,      t, vA0, vB0, uA0, uB0, wA0, wB0, pA0, pB0, fmA0, fmB0);
    phases12(Csh1, claim + Nn, t, vA1, vB1, uA1, uB1, wA1, wB1, pA1, pB1, fmA1, fmB1);

    // ---- Phase 3: interleaved dual-batch Dijkstra ----
    int st0 = 0, st1 = 0;
    int i0 = 1, i1 = 1;
    float su0 = 0.0f, su1 = 0.0f;
    int j00 = 0, j01 = 0;
    float minvA0 = FLT_MAX, minvB0 = FLT_MAX, minvA1 = FLT_MAX, minvB1 = FLT_MAX;
    int wayA0 = 0, wayB0 = 0, wayA1 = 0, wayB1 = 0;
    float c00 = 0.0f, c10 = 0.0f, c01 = 0.0f, c11 = 0.0f;
    bool usedA0 = false, usedB0 = false, usedA1 = false, usedB1 = false;
    bool rUA0 = false, rUB0 = false, rUA1 = false, rUB1 = false;

    while (st0 != 2 || st1 != 2) {
        dijk_tick(Csh0, t, st0, fmA0, fmB0, i0, su0, j00,
                  vA0, vB0, uA0, uB0, wA0, wB0, pA0, pB0,
                  minvA0, minvB0, wayA0, wayB0, c00, c10,
                  usedA0, usedB0, rUA0, rUB0);
        dijk_tick(Csh1, t, st1, fmA1, fmB1, i1, su1, j01,
                  vA1, vB1, uA1, uB1, wA1, wB1, pA1, pB1,
                  minvA1, minvB1, wayA1, wayB1, c01, c11,
                  usedA1, usedB1, rUA1, rUB1);
    }

    // ---- gather matched costs for both batches ----
    float tot = Csh0[(pA0 - 1) * Nn + t] + Csh0[(pB0 - 1) * Nn + t + 64]
              + Csh1[(pA1 - 1) * Nn + t] + Csh1[(pB1 - 1) * Nn + t + 64];
    tot = wave_sum_lane63(tot);

    if (t == 63) {
        // loss = sum_b (total_b / N) / B * WEIGHT
        atomicAdd(out, tot * (1.0f / ((float)Nn * (float)Bc)));
    }
}

extern "C" void kernel_launch(void* const* d_in, const int* in_sizes, int n_in,
                              void* d_out, int out_size, void* d_ws, size_t ws_size,
                              hipStream_t stream) {
    const float* P = (const float*)d_in[0];   // batch_prediction  [32,128,256] f32
    const float* G = (const float*)d_in[1];   // batch_groundtruth [32,128,256] f32
    float* out = (float*)d_out;               // [1] f32
    float* C = (float*)d_ws;                  // cost scratch: 32*128*128 f32 = 2 MB

    const int lds_bytes = 2 * Nn * Nn * (int)sizeof(float) + 2 * Nn * (int)sizeof(int);

    static bool attr_set = false;
    if (!attr_set) {
        (void)hipFuncSetAttribute((const void*)hungarian_kernel,
                                  hipFuncAttributeMaxDynamicSharedMemorySize,
                                  lds_bytes);
        attr_set = true;
    }

    dim3 gcost(Nn, Bc);
    cost_kernel<<<gcost, 64, 0, stream>>>(P, G, C, out);
    hungarian_kernel<<<Bc / 2, 64, lds_bytes, stream>>>(C, out);
}

// Round 7
// 533.243 us; speedup vs baseline: 2.7471x; 2.7471x over previous
//
#include <hip/hip_runtime.h>
#include <float.h>

// Problem constants (match reference): B=32, N=M=128, D=256, WEIGHT=1.0
#define Bc 32
#define Nn 128
#define Dd 256

// ---------------------------------------------------------------------------
// DPP helpers. dpp_ctrl must be a compile-time constant.
// Reduction to lane 63: ror 1/2/4/8 within 16-lane rows (all sources valid),
// then row_bcast:15 / row_bcast:31 fold rows; lane 63 ends with the full
// 64-lane reduction (standard CDNA pattern).
// ---------------------------------------------------------------------------
template <int CTRL>
__device__ __forceinline__ float dpp_addsrc(float x) {  // old = 0 for untouched lanes
    return __int_as_float(__builtin_amdgcn_update_dpp(0, __float_as_int(x), CTRL,
                                                      0xf, 0xf, false));
}
__device__ __forceinline__ float wave_sum_lane63(float x) {
    x += dpp_addsrc<0x121>(x);  // row_ror:1
    x += dpp_addsrc<0x122>(x);  // row_ror:2
    x += dpp_addsrc<0x124>(x);  // row_ror:4
    x += dpp_addsrc<0x128>(x);  // row_ror:8
    x += dpp_addsrc<0x142>(x);  // row_bcast:15
    x += dpp_addsrc<0x143>(x);  // row_bcast:31
    return x;                   // lane 63 = total
}

template <int CTRL>
__device__ __forceinline__ unsigned dpp_movu(unsigned x) {  // old = UINT_MAX
    return (unsigned)__builtin_amdgcn_update_dpp((int)0xFFFFFFFFu, (int)x, CTRL,
                                                 0xf, 0xf, false);
}
__device__ __forceinline__ unsigned wave_umin_lane63(unsigned x) {
    x = min(x, dpp_movu<0x121>(x));
    x = min(x, dpp_movu<0x122>(x));
    x = min(x, dpp_movu<0x124>(x));
    x = min(x, dpp_movu<0x128>(x));
    x = min(x, dpp_movu<0x142>(x));
    x = min(x, dpp_movu<0x143>(x));
    return x;                   // lane 63 = min of all 64 lanes
}

template <int CTRL>
__device__ __forceinline__ float dpp_movf(float x) {  // old = FLT_MAX
    return __int_as_float(__builtin_amdgcn_update_dpp(0x7f7fffff, __float_as_int(x),
                                                      CTRL, 0xf, 0xf, false));
}
// two-min (min, second-min counting multiplicity) combine step
template <int CTRL>
__device__ __forceinline__ void dpp2min_step(float& m1, float& m2) {
    float o1 = dpp_movf<CTRL>(m1);
    float o2 = dpp_movf<CTRL>(m2);
    float n1 = fminf(m1, o1);
    m2 = fminf(fmaxf(m1, o1), fminf(m2, o2));
    m1 = n1;
}

__device__ __forceinline__ float readlane_f(float v, int lane) {
    return __int_as_float(__builtin_amdgcn_readlane(__float_as_int(v), lane));
}

// ---------------------------------------------------------------------------
// Kernel 1: pairwise MSE cost.  cost[b,i,j] = sum_d (p[b,i,d]-g[b,j,d])^2 / D
// One wave per (b,i) row; lane t holds float4 of p[b,i]. DPP-add reduction.
// XCD-locality swizzle (NEW): 1-D grid, batch b = xcd + 8*(slot>>7), row
// i = slot&127, where xcd = blockIdx.x&7, slot = blockIdx.x>>3. With the
// empirical round-robin block->XCD dispatch, each XCD touches only 4 of the
// 32 G-matrices (4 x 128 KB = 512 KB), so the 128x re-read of G[b] by the
// 128 row-blocks of batch b stays L2-resident instead of streaming all 32
// batches through every XCD's L2 (the old (x=i,y=b) grid did exactly that).
// Mapping is bijective: blockIdx.x = xcd + 8*((b>>3)*128 + i).
// Block 0 lane 0 also zeroes the output scalar (stream-ordered before the
// hungarian kernel's atomicAdds).
// ---------------------------------------------------------------------------
__global__ __launch_bounds__(64) void cost_kernel(const float* __restrict__ P,
                                                  const float* __restrict__ G,
                                                  float* __restrict__ C,
                                                  float* __restrict__ out) {
    const int blk = blockIdx.x;
    const int xcd = blk & 7;
    const int slot = blk >> 3;
    const int b = xcd + 8 * (slot >> 7);   // batch
    const int i = slot & 127;              // row
    const int t = threadIdx.x;

    if (blk == 0 && t == 0) *out = 0.0f;

    const float4 pv = ((const float4*)(P + ((size_t)b * Nn + i) * Dd))[t];
    const float4* g4 = (const float4*)(G + (size_t)b * Nn * Dd);
    float* crow = C + ((size_t)b * Nn + i) * Nn;

    for (int j = 0; j < Nn; j += 2) {
        float4 gv0 = g4[(size_t)j * 64 + t];
        float4 gv1 = g4[(size_t)(j + 1) * 64 + t];
        float dx0 = pv.x - gv0.x, dy0 = pv.y - gv0.y, dz0 = pv.z - gv0.z, dw0 = pv.w - gv0.w;
        float dx1 = pv.x - gv1.x, dy1 = pv.y - gv1.y, dz1 = pv.z - gv1.z, dw1 = pv.w - gv1.w;
        float s0 = dx0 * dx0 + dy0 * dy0 + dz0 * dz0 + dw0 * dw0;
        float s1 = dx1 * dx1 + dy1 * dy1 + dz1 * dz1 + dw1 * dw1;
        s0 = wave_sum_lane63(s0);
        s1 = wave_sum_lane63(s1);
        if (t == 63) {
            crow[j]     = s0 * (1.0f / (float)Dd);
            crow[j + 1] = s1 * (1.0f / (float)Dd);
        }
    }
}

// ---------------------------------------------------------------------------
// Kernel 2: LAPJV-style Hungarian, one single-wave block per batch.
// VERBATIM the Round-2 kernel (best measured: 448.6 us hungarian, 534.6 us
// total, absmax 0.0). Six rounds of evidence say this structure is within
// ~20% of its serial-latency floor: chain surgery x3 = +/-4%, dual
// tightening = -3.5% (kept, this version), tau-greedy = 0% (never fires),
// dual-batch interleave = provably >= 0 gain (wall time is the slowest
// single batch's dependent chain; interleaving can't shorten it).
//   Phase 1:   column reduction + greedy zero-edge match.
//   Phase 1.5: reduction transfer.
//   Phase 2:   augmenting row reduction (2 bounded passes with steal).
//   Phase 3:   Dijkstra shortest augmenting path, packed-key argmin + LDS
//              next-row prefetch.
// ---------------------------------------------------------------------------
__global__ __launch_bounds__(64) void hungarian_kernel(const float* __restrict__ Call,
                                                       float* __restrict__ out) {
    const int b = blockIdx.x;
    const int t = threadIdx.x;

    __shared__ float Csh[Nn * Nn];  // 64 KB
    __shared__ int claim[Nn];

    // stage this batch's cost matrix into LDS (coalesced float4)
    {
        const float4* src = (const float4*)(Call + (size_t)b * Nn * Nn);
        float4* dst = (float4*)Csh;
#pragma unroll
        for (int k = 0; k < (Nn * Nn / 4) / 64; ++k)
            dst[k * 64 + t] = src[k * 64 + t];
    }
    claim[t] = 0x7fffffff;
    claim[t + 64] = 0x7fffffff;
    __syncthreads();

    // ---- Phase 1: column reduction ----
    float bestA = FLT_MAX, bestB = FLT_MAX;
    int argA = 0, argB = 0;  // 0-based argmin row per owned column
    for (int i = 0; i < Nn; ++i) {
        float c0 = Csh[i * Nn + t];
        float c1 = Csh[i * Nn + t + 64];
        if (c0 < bestA) { bestA = c0; argA = i; }
        if (c1 < bestB) { bestB = c1; argB = i; }
    }
    float vA = bestA, vB = bestB;     // column potentials (reduced costs >= 0, u=0)
    atomicMin(&claim[argA], t);       // column (0-based) claims its argmin row
    atomicMin(&claim[argB], t + 64);
    __syncthreads();

    float uA = 0.0f, uB = 0.0f;       // row potentials (rows t+1, t+65)
    float wA = 0.0f, wB = 0.0f;       // w[j] = u[p[j]]
    int pA = 0, pB = 0;               // row assigned to column (0 = free)
    if (claim[argA] == t)      pA = argA + 1;
    if (claim[argB] == t + 64) pB = argB + 1;

    unsigned long long fmA = __ballot(claim[t] == 0x7fffffff);       // free rows 1..64
    unsigned long long fmB = __ballot(claim[t + 64] == 0x7fffffff);  // free rows 65..128

    // ---- Phase 1.5: reduction transfer (serial over assigned rows) ----
    {
        int rcA = claim[t];        // column (0-based) that won row t+1, or INT_MAX
        int rcB = claim[t + 64];   // column that won row t+65, or INT_MAX
        float c0 = Csh[t];         // prefetch row 0
        float c1 = Csh[t + 64];
        for (int r = 0; r < Nn; ++r) {
            int s_c = __builtin_amdgcn_readlane((r & 64) ? rcB : rcA, r & 63);
            int pr = (r + 1) & (Nn - 1);          // wrap-safe next-row prefetch
            float n0 = Csh[pr * Nn + t];
            float n1 = Csh[pr * Nn + t + 64];
            if (s_c != 0x7fffffff) {              // row r+1 is assigned to col s_c
                bool ex0 = (t == s_c);            // exclude the assigned column
                bool ex1 = (t + 64 == s_c);
                float cur0 = ex0 ? FLT_MAX : (c0 - vA);
                float cur1 = ex1 ? FLT_MAX : (c1 - vB);
                float m = fminf(cur0, cur1);
                m = fminf(m, dpp_movf<0x121>(m));
                m = fminf(m, dpp_movf<0x122>(m));
                m = fminf(m, dpp_movf<0x124>(m));
                m = fminf(m, dpp_movf<0x128>(m));
                m = fminf(m, dpp_movf<0x142>(m));
                m = fminf(m, dpp_movf<0x143>(m));
                float mu = readlane_f(m, 63);     // mu >= 0 (v_j <= col min)
                if (ex0) { vA -= mu; wA = mu; }   // v[j1] -= mu; w[j1] = u[row]
                if (ex1) { vB -= mu; wB = mu; }
                if (t == (r & 63)) {              // u[row r+1] = mu
                    if (r < 64) uA = mu; else uB = mu;
                }
            }
            c0 = n0; c1 = n1;
        }
    }

    // ---- Phase 2: augmenting row reduction (2 passes, bounded, with steal) ----
    for (int pass = 0; pass < 2; ++pass) {
        if (!(fmA | fmB)) break;
        unsigned long long remA = fmA, remB = fmB;
        int guard = 0;
        while ((remA | remB) != 0ull && guard++ < 256) {
            int l, i, slotR;
            if (remA) { l = __ffsll(remA) - 1; remA &= remA - 1; i = l + 1;  slotR = 0;
                        if (!((fmA >> l) & 1)) continue; }
            else      { l = __ffsll(remB) - 1; remB &= remB - 1; i = l + 65; slotR = 1;
                        if (!((fmB >> l) & 1)) continue; }

            const float* crow = &Csh[(i - 1) * Nn];
            float cur0 = crow[t] - vA;
            float cur1 = crow[t + 64] - vB;
            float m1 = fminf(cur0, cur1);
            float m2 = fmaxf(cur0, cur1);
            dpp2min_step<0x121>(m1, m2);
            dpp2min_step<0x122>(m1, m2);
            dpp2min_step<0x124>(m1, m2);
            dpp2min_step<0x128>(m1, m2);
            dpp2min_step<0x142>(m1, m2);
            dpp2min_step<0x143>(m1, m2);
            float s_m1 = readlane_f(m1, 63);
            float s_m2 = readlane_f(m2, 63);

            unsigned long long b0 = __ballot(cur0 == s_m1);
            unsigned long long b1 = __ballot(cur1 == s_m1);
            int j1 = b0 ? __ffsll(b0) : (__ffsll(b1) + 64);  // 1-based column
            int lane1 = (j1 - 1) & 63, slot1 = (j1 - 1) >> 6;

            // u[i] = second-min  (dual-feasible regardless of what follows)
            if (t == l) { if (slotR == 0) uA = s_m2; else uB = s_m2; }

            int k0 = __builtin_amdgcn_readlane(slot1 ? pB : pA, lane1);
            bool strict = (s_m1 < s_m2);
            if (!strict && k0 != 0) continue;  // tie & occupied: leave row free

            if (t == lane1) {
                if (slot1 == 0) { vA += s_m1 - s_m2; pA = i; wA = s_m2; }
                else            { vB += s_m1 - s_m2; pB = i; wB = s_m2; }
            }
            if (slotR == 0) fmA &= ~(1ull << l); else fmB &= ~(1ull << l);
            if (k0 != 0) {  // stolen row becomes free again
                int kl = (k0 - 1) & 63;
                if (k0 <= 64) { fmA |= 1ull << kl; remA |= 1ull << kl; }
                else          { fmB |= 1ull << kl; remB |= 1ull << kl; }
            }
        }
    }

    // ---- Phase 3: Dijkstra shortest augmenting path for leftover free rows ----
    for (int slotR = 0; slotR < 2; ++slotR) {
        unsigned long long mask = slotR ? fmB : fmA;
        while (mask) {
            int l = __ffsll(mask) - 1;
            mask &= mask - 1;
            int i = l + 1 + slotR * 64;  // 1-based free row

            float minvA = FLT_MAX, minvB = FLT_MAX;
            int wayA = 0, wayB = 0;
            bool usedA = false, usedB = false;
            bool rUA = false, rUB = false;
            if (t == l) { if (slotR == 0) rUA = true; else rUB = true; }

            int s_j0 = 0;
            float s_u = readlane_f(slotR ? uB : uA, l);  // u[i] from ARR
            int s_j1;

            // initial row load (row i)
            float c0 = Csh[(i - 1) * Nn + t];
            float c1 = Csh[(i - 1) * Nn + t + 64];

            for (;;) {
                // relax free columns (clamped >= 0 so packed keys order correctly)
                if (!usedA) {
                    float cur = fmaxf(c0 - s_u - vA, 0.0f);
                    if (cur < minvA) { minvA = cur; wayA = s_j0; }
                }
                if (!usedB) {
                    float cur = fmaxf(c1 - s_u - vB, 0.0f);
                    if (cur < minvB) { minvB = cur; wayB = s_j0; }
                }

                // packed-key argmin: (value_bits & ~0xFF) | col0based
                unsigned kA = (__float_as_uint(usedA ? FLT_MAX : minvA) & 0xFFFFFF00u)
                              | (unsigned)t;
                unsigned kB = (__float_as_uint(usedB ? FLT_MAX : minvB) & 0xFFFFFF00u)
                              | (unsigned)(t + 64);
                unsigned k = wave_umin_lane63(min(kA, kB));
                unsigned s_key = (unsigned)__builtin_amdgcn_readlane((int)k, 63);
                float s_delta = __uint_as_float(s_key & 0xFFFFFF00u);
                s_j1 = (int)(s_key & 0xFFu) + 1;  // 1-based column

                // lookup p,w for j1 (needed for prefetch — do before dual updates)
                int lane1 = (s_j1 - 1) & 63;
                int slot1 = (s_j1 - 1) >> 6;
                int s_p = __builtin_amdgcn_readlane(slot1 ? pB : pA, lane1);
                float s_w = readlane_f(slot1 ? wB : wA, lane1);

                // prefetch next cost row (safe index; latency hides under updates)
                int nrow = (s_p > 0 ? s_p : 1) - 1;
                float nc0 = Csh[nrow * Nn + t];
                float nc1 = Csh[nrow * Nn + t + 64];

                // dual updates (independent of prefetch data)
                if (usedA) { vA -= s_delta; wA += s_delta; }
                else       { minvA = fmaxf(minvA - s_delta, 0.0f); }
                if (usedB) { vB -= s_delta; wB += s_delta; }
                else       { minvB = fmaxf(minvB - s_delta, 0.0f); }
                if (rUA) uA += s_delta;
                if (rUB) uB += s_delta;

                if (s_p == 0) break;  // augmenting path found at s_j1

                if (t == lane1) { if (slot1 == 0) usedA = true; else usedB = true; }
                {
                    int r = s_p - 1;
                    if (t == (r & 63)) { if ((r >> 6) == 0) rUA = true; else rUB = true; }
                }
                s_j0 = s_j1;
                s_u = s_w;
                c0 = nc0;
                c1 = nc1;
            }

            // augment along way[] chain (uniform serial walk)
            int s_j = s_j1;
            while (s_j) {
                int lane = (s_j - 1) & 63;
                int slot = (s_j - 1) >> 6;
                int s_jprev = __builtin_amdgcn_readlane(slot ? wayB : wayA, lane);
                int s_pnew;
                if (s_jprev == 0) {
                    s_pnew = i;
                } else {
                    int lp = (s_jprev - 1) & 63;
                    int sp = (s_jprev - 1) >> 6;
                    s_pnew = __builtin_amdgcn_readlane(sp ? pB : pA, lp);
                }
                int rl = (s_pnew - 1) & 63;
                int rs = (s_pnew - 1) >> 6;
                float s_unew = readlane_f(rs ? uB : uA, rl);  // w[j] = u[p[j]]
                if (t == lane) {
                    if (slot == 0) { pA = s_pnew; wA = s_unew; }
                    else           { pB = s_pnew; wB = s_unew; }
                }
                s_j = s_jprev;
            }
        }
    }

    // ---- gather matched costs: column jA=t+1 -> row pA, etc. ----
    float tot = Csh[(pA - 1) * Nn + t] + Csh[(pB - 1) * Nn + t + 64];
    tot = wave_sum_lane63(tot);

    if (t == 63) {
        // loss = sum_b (total_b / N) / B * WEIGHT
        atomicAdd(out, tot * (1.0f / ((float)Nn * (float)Bc)));
    }
}

extern "C" void kernel_launch(void* const* d_in, const int* in_sizes, int n_in,
                              void* d_out, int out_size, void* d_ws, size_t ws_size,
                              hipStream_t stream) {
    const float* P = (const float*)d_in[0];   // batch_prediction  [32,128,256] f32
    const float* G = (const float*)d_in[1];   // batch_groundtruth [32,128,256] f32
    float* out = (float*)d_out;               // [1] f32
    float* C = (float*)d_ws;                  // cost scratch: 32*128*128 f32 = 2 MB

    cost_kernel<<<Bc * Nn, 64, 0, stream>>>(P, G, C, out);
    hungarian_kernel<<<Bc, 64, 0, stream>>>(C, out);
}